// Round 9
// baseline (530.561 us; speedup 1.0000x reference)
//
#include <hip/hip_runtime.h>
#include <hip/hip_bf16.h>
#include <stdint.h>

typedef __attribute__((ext_vector_type(8))) short short8;
typedef __attribute__((ext_vector_type(4))) short bf16x4;
typedef __attribute__((ext_vector_type(4))) float f32x4;

#define S_LEN   4096
#define HID_DIM 2048
#define NHEAD   16
#define NKV     4
#define DHEAD   128
#define QPG     4
#define GROUP   768   // (QPG+2)*DHEAD
#define TOTAL   3072  // NKV*GROUP

#define NSLOT   192   // 128 heavy + 64 light (pairs 4..7), 256-row slots

__device__ __forceinline__ ushort f2bf(float f) {
    union { float f; uint32_t u; } c; c.f = f;
    uint32_t u = c.u;
    u += 0x7fff + ((u >> 16) & 1);   // RNE
    return (ushort)(u >> 16);
}

// PV matrix op: D = A(4xbf16) * B(4xbf16) + C, 16x16x16. Builtin preferred
// (lets the allocator place the accumulator in the unified AGPR/VGPR file);
// inline-asm only as last resort (R7: asm "+v" constraints caused a
// catastrophic accumulator spill, 84 VGPR + 398 MB scratch).
__device__ __forceinline__ f32x4 mfma16_bf16(bf16x4 a, bf16x4 b, f32x4 c) {
#if __has_builtin(__builtin_amdgcn_mfma_f32_16x16x16_bf16)
    return __builtin_amdgcn_mfma_f32_16x16x16_bf16(a, b, c, 0, 0, 0);
#elif __has_builtin(__builtin_amdgcn_mfma_f32_16x16x16bf16_1k)
    return __builtin_amdgcn_mfma_f32_16x16x16bf16_1k(a, b, c, 0, 0, 0);
#else
    asm("v_mfma_f32_16x16x16_bf16 %0, %1, %2, %0" : "+v"(c) : "v"(a), "v"(b));
    return c;
#endif
}

__device__ __forceinline__ void gld_lds16(const void* g, void* l) {
    __builtin_amdgcn_global_load_lds(
        (const __attribute__((address_space(1))) void*)g,
        (__attribute__((address_space(3))) void*)l, 16, 0, 0);
}

// LDS-only barrier: staged K/V visibility via lgkmcnt(0); register-destined
// global prefetch loads may stay in flight (R6: neutral vs full drain).
__device__ __forceinline__ void lds_barrier() {
    asm volatile("s_waitcnt lgkmcnt(0)\n\ts_barrier" ::: "memory");
}

// ---------------------------------------------------------------------------
// fp32 -> bf16 convert. mode 1: scale q-head rows of wqkv by 1/sqrt(D)
// ---------------------------------------------------------------------------
__global__ __launch_bounds__(256)
void cvt_f32_bf16(const float* __restrict__ src, ushort* __restrict__ dst,
                  int n4, int mode)
{
    int i = blockIdx.x * blockDim.x + threadIdx.x;
    int stride = gridDim.x * blockDim.x;
    for (; i < n4; i += stride) {
        float sc = 1.0f;
        if (mode == 1) {
            int row = i >> 9;                      // (i*4)/2048
            sc = ((row % GROUP) < QPG * DHEAD) ? 0.088388347648318447f : 1.0f;
        }
        float4 v = ((const float4*)src)[i];
        ushort4 o;
        o.x = f2bf(v.x * sc); o.y = f2bf(v.y * sc);
        o.z = f2bf(v.z * sc); o.w = f2bf(v.w * sc);
        ((ushort4*)dst)[i] = o;
    }
}

__global__ __launch_bounds__(256)
void zero_f4(float4* __restrict__ p, int n4)
{
    int i = blockIdx.x * blockDim.x + threadIdx.x;
    int stride = gridDim.x * blockDim.x;
    float4 z = {0.f, 0.f, 0.f, 0.f};
    for (; i < n4; i += stride) p[i] = z;
}

// ---------------------------------------------------------------------------
// C[M,N] = A[M,K] * B[N,K]^T (bf16 in, fp32 accum). m97-style staging.
// ---------------------------------------------------------------------------
__device__ __forceinline__ void store_c(ushort* C, size_t idx, float v) { C[idx] = f2bf(v); }
__device__ __forceinline__ void store_c(float*  C, size_t idx, float v) { C[idx] = v; }

template <typename OutT, bool WRITE_VT>
__global__ __launch_bounds__(256, 2)
void gemm_bt(const ushort* __restrict__ A, const ushort* __restrict__ B,
             OutT* __restrict__ C, ushort* __restrict__ VT,
             int M, int N, int K)
{
    __shared__ alignas(16) ushort Asl[128 * 32];
    __shared__ alignas(16) ushort Bsl[128 * 32];

    const int tid  = threadIdx.x;
    const int wave = tid >> 6;
    const int lane = tid & 63;
    const int quad = lane >> 4;
    const int l15  = lane & 15;
    const int wr   = wave >> 1;
    const int wc   = wave & 1;
    const int m0   = blockIdx.y * 128;
    const int n0   = blockIdx.x * 128;

    f32x4 acc[4][4];
#pragma unroll
    for (int i = 0; i < 4; i++)
#pragma unroll
        for (int j = 0; j < 4; j++) acc[i][j] = (f32x4)0.0f;

    for (int kb = 0; kb < K; kb += 32) {
        __syncthreads();
#pragma unroll
        for (int r = 0; r < 2; r++) {
            int idx = tid + r * 256;
            int row = idx >> 2, c8 = idx & 3;
            char* la = (char*)Asl + (size_t)(wave * 64 + r * 256) * 16;
            char* lb = (char*)Bsl + (size_t)(wave * 64 + r * 256) * 16;
            gld_lds16(A + (size_t)(m0 + row) * K + kb + c8 * 8, la);
            gld_lds16(B + (size_t)(n0 + row) * K + kb + c8 * 8, lb);
        }
        __syncthreads();

        short8 af[4], bf[4];
#pragma unroll
        for (int i = 0; i < 4; i++)
            af[i] = *(const short8*)(&Asl[(wr * 64 + i * 16 + l15) * 32 + quad * 8]);
#pragma unroll
        for (int j = 0; j < 4; j++)
            bf[j] = *(const short8*)(&Bsl[(wc * 64 + j * 16 + l15) * 32 + quad * 8]);
#pragma unroll
        for (int i = 0; i < 4; i++)
#pragma unroll
            for (int j = 0; j < 4; j++)
                acc[i][j] = __builtin_amdgcn_mfma_f32_16x16x32_bf16(
                    af[i], bf[j], acc[i][j], 0, 0, 0);
    }

#pragma unroll
    for (int i = 0; i < 4; i++)
#pragma unroll
        for (int j = 0; j < 4; j++)
#pragma unroll
            for (int r = 0; r < 4; r++) {
                int row = m0 + wr * 64 + i * 16 + quad * 4 + r;
                int col = n0 + wc * 64 + j * 16 + l15;
                store_c(C, (size_t)row * N + col, acc[i][j][r]);
            }

    if (WRITE_VT) {
        int cb = n0 >> 7;
        if (cb % 6 == 5) {          // V-region column block
            int g = cb / 6;
#pragma unroll
            for (int i = 0; i < 4; i++)
#pragma unroll
                for (int j = 0; j < 4; j++) {
                    int d    = wc * 64 + j * 16 + l15;
                    int row0 = m0 + wr * 64 + i * 16 + quad * 4;
                    ushort4 pk;
                    pk.x = f2bf(acc[i][j][0]); pk.y = f2bf(acc[i][j][1]);
                    pk.z = f2bf(acc[i][j][2]); pk.w = f2bf(acc[i][j][3]);
                    *(ushort4*)(VT + (size_t)(g * 128 + d) * S_LEN + row0) = pk;
                }
        }
    }
}

// ---------------------------------------------------------------------------
// Causal GQA flash attention. R8's winning 8-wave dbuf pipeline (512 thr,
// 256-row Q strips, 32-row KV tiles, 1 lgkm-barrier/tile, 2 blocks/CU =
// 16 waves/CU) with the P LDS round-trip REMOVED via swapped QK^T:
//   S^T = mfma_16x16x32(K, Q): lane holds S^T[kv = quad*4+r +16ki][q = l15]
//   softmax + pack in-lane -> P^T bf16x4 per ki -- k = quad*4..+3 is
//   EXACTLY the 16x16x16 B-fragment layout, so PV consumes P from registers:
//   O^T += mfma_16x16x16(V^T_frag, P^T)   (builtin; R7's asm variant spilled)
// Pl deleted; a kept-alive LDS pad pins total at ~55 KB so the compiler's
// occupancy heuristic sees the same 2-blocks/CU environment as R8 (VGPR 96).
// Geometry/slots identical to R8: (head, pair p, quarter), heavy 15-p
// (H = 128-8p) ++ light p (L = 8p+8) = 136 = 4*34 units; NSLOT = 192.
// ---------------------------------------------------------------------------
__global__ __launch_bounds__(512, 2)
void flash_attn(const ushort* __restrict__ qkv, const ushort* __restrict__ VT,
                ushort* __restrict__ out, float* __restrict__ o_slot,
                float* __restrict__ l_slot)
{
    const int b    = blockIdx.x;
    const int head = b >> 5;                  // head-major
    const int pair = (b >> 2) & 7;            // 0..7
    const int quar = b & 3;                   // 0..3

    const int g    = head >> 2;
    const int qh   = head & 3;
    const int H    = 128 - 8 * pair;          // heavy strip tiles (72..128)
    const int L    = 8 * pair + 8;            // light strip tiles (8..64)
    const int c0   = quar * 34;
    const int c1   = c0 + 34;

    const int tid  = threadIdx.x;
    const int wave = tid >> 6;                // 0..7
    const int lane = tid & 63;
    const int quad = lane >> 4;
    const int l15  = lane & 15;

    __shared__ alignas(16) ushort Kl[2][32][136];   // [buf][j][d]   17,408 B
    __shared__ alignas(16) ushort Vt[2][128][40];   // [buf][d][j]   20,480 B
    __shared__ alignas(16) ushort ldspin[8704];     // occupancy pin  17,408 B
    // keep the pin allocated (escapes into asm black box, never touched)
    asm volatile("" :: "v"((uintptr_t)&ldspin[0]));

    int seg_s[2], seg_t0[2], seg_t1[2], seg_slot[2];
    int nseg = 0;
    {
        int h1 = (c1 < H) ? c1 : H;           // heavy piece [c0, h1)
        if (c0 < h1) {
            seg_s[nseg] = 15 - pair; seg_t0[nseg] = c0; seg_t1[nseg] = h1;
            seg_slot[nseg] = head * 8 + pair;           // heavy slot 0..127
            nseg++;
        }
        int l0 = (c0 > H) ? c0 : H;           // light piece [l0, c1) global units
        if (l0 < c1) {
            int lt0 = l0 - H, lt1 = c1 - H;
            int whole = (lt0 == 0) & (lt1 == L);        // pairs 0..3
            seg_s[nseg] = pair; seg_t0[nseg] = lt0; seg_t1[nseg] = lt1;
            seg_slot[nseg] = whole ? -1 : (128 + head * 4 + (pair - 4));
            nseg++;
        }
    }

    const int koff = g * GROUP + QPG * DHEAD;

    for (int s = 0; s < nseg; s++) {
        const int t0 = seg_t0[s];
        const int t1 = seg_t1[s];
        const int q0 = seg_s[s] * 256;

        // Q fragments (B-operand of swapped QK^T: lane q-row = l15)
        short8 qf[2][4];
#pragma unroll
        for (int qi = 0; qi < 2; qi++) {
            int row = q0 + wave * 32 + qi * 16 + l15;
            const ushort* qp = qkv + (size_t)row * TOTAL + g * GROUP + qh * DHEAD + quad * 8;
#pragma unroll
            for (int ks = 0; ks < 4; ks++)
                qf[qi][ks] = *(const short8*)(qp + ks * 32);
        }

        f32x4 o[2][8];                        // O^T acc: [qi][df]
#pragma unroll
        for (int qi = 0; qi < 2; qi++)
#pragma unroll
            for (int df = 0; df < 8; df++) o[qi][df] = (f32x4)0.0f;
        float l_vec[2] = {0.0f, 0.0f};

        // per-thread staging slots (32-row tile: 512 f4 K + 512 f4 V, 512 thr)
        const int kr = tid >> 4, kc = tid & 15;       // K rows 0..31
        const int vd = tid >> 2, vc = tid & 3;        // V rows 0..127

        float4 kpre, vpre;
        // prologue: load tile t0, write buf 0, prefetch t0+1
        kpre = *(const float4*)(qkv + (size_t)(t0 * 32 + kr) * TOTAL + koff + kc * 8);
        vpre = *(const float4*)(VT + (size_t)(g * 128 + vd) * S_LEN + t0 * 32 + vc * 8);
        // previous segment's last-iteration barrier guarantees buf0 is free
        *(float4*)(&Kl[0][kr][kc * 8]) = kpre;
        *(float4*)(&Vt[0][vd][vc * 8]) = vpre;
        if (t0 + 1 < t1) {
            const int j1 = (t0 + 1) * 32;
            kpre = *(const float4*)(qkv + (size_t)(j1 + kr) * TOTAL + koff + kc * 8);
            vpre = *(const float4*)(VT + (size_t)(g * 128 + vd) * S_LEN + j1 + vc * 8);
        }
        __syncthreads();

        for (int t = t0; t < t1; t++) {
            const int cur = (t - t0) & 1;

            // stage tile t+1 into the other buffer (overlaps this compute)
            if (t + 1 < t1) {
                *(float4*)(&Kl[cur ^ 1][kr][kc * 8]) = kpre;
                *(float4*)(&Vt[cur ^ 1][vd][vc * 8]) = vpre;
                if (t + 2 < t1) {
                    const int j2 = (t + 2) * 32;
                    kpre = *(const float4*)(qkv + (size_t)(j2 + kr) * TOTAL + koff + kc * 8);
                    vpre = *(const float4*)(VT + (size_t)(g * 128 + vd) * S_LEN + j2 + vc * 8);
                }
            }

            const int j0 = t * 32;
            // S^T = K Q^T : sacc[ki][qi], lane: kv = quad*4+r (+16ki), q = l15
            f32x4 sacc[2][2];
#pragma unroll
            for (int ki = 0; ki < 2; ki++)
#pragma unroll
                for (int qi = 0; qi < 2; qi++) sacc[ki][qi] = (f32x4)0.0f;
            __builtin_amdgcn_s_setprio(1);
#pragma unroll
            for (int ki = 0; ki < 2; ki++)
#pragma unroll
                for (int ks = 0; ks < 4; ks++) {
                    short8 kf = *(const short8*)(&Kl[cur][ki * 16 + l15][ks * 32 + quad * 8]);
#pragma unroll
                    for (int qi = 0; qi < 2; qi++)
                        sacc[ki][qi] = __builtin_amdgcn_mfma_f32_16x16x32_bf16(
                            kf, qf[qi][ks], sacc[ki][qi], 0, 0, 0);
                }
            __builtin_amdgcn_s_setprio(0);

            // exp (no max) + causal mask + l accumulation + in-lane bf16 pack
            bf16x4 pb[2][2];                  // [qi][ki] packed P^T
#pragma unroll
            for (int qi = 0; qi < 2; qi++) {
                const int qmin = q0 + wave * 32 + qi * 16;   // wave-uniform
                float rs = 0.0f;
                if (j0 + 31 > qmin) {
                    const int q_g = qmin + l15;
#pragma unroll
                    for (int ki = 0; ki < 2; ki++)
#pragma unroll
                        for (int r = 0; r < 4; r++) {
                            float e = __expf(sacc[ki][qi][r]);
                            int kv_g = j0 + ki * 16 + quad * 4 + r;
                            e = (kv_g > q_g) ? 0.0f : e;
                            sacc[ki][qi][r] = e;
                            rs += e;
                        }
                } else {
#pragma unroll
                    for (int ki = 0; ki < 2; ki++)
#pragma unroll
                        for (int r = 0; r < 4; r++) {
                            float e = __expf(sacc[ki][qi][r]);
                            sacc[ki][qi][r] = e;
                            rs += e;
                        }
                }
                l_vec[qi] += rs;
#pragma unroll
                for (int ki = 0; ki < 2; ki++) {
                    union { ushort4 u; bf16x4 v; } pw;
                    pw.u.x = f2bf(sacc[ki][qi][0]);
                    pw.u.y = f2bf(sacc[ki][qi][1]);
                    pw.u.z = f2bf(sacc[ki][qi][2]);
                    pw.u.w = f2bf(sacc[ki][qi][3]);
                    pb[qi][ki] = pw.v;
                }
            }

            // O^T += V^T P : A-frag = V^T (lane: d=l15, k=quad*4..+3 per ki),
            //                B-frag = P^T (lane: q=l15, k=quad*4..+3) in regs.
            __builtin_amdgcn_s_setprio(1);
#pragma unroll
            for (int df = 0; df < 8; df++)
#pragma unroll
                for (int ki = 0; ki < 2; ki++) {
                    bf16x4 vf = *(const bf16x4*)(&Vt[cur][df * 16 + l15][ki * 16 + quad * 4]);
#pragma unroll
                    for (int qi = 0; qi < 2; qi++)
                        o[qi][df] = mfma16_bf16(vf, pb[qi][ki], o[qi][df]);
                }
            __builtin_amdgcn_s_setprio(0);

            // buf^1 staged for next iter; prefetch stays in flight.
            lds_barrier();
        }

        // epilogue. O^T lane layout: d = df*16 + quad*4 + r, q = l15 (+16qi).
        if (seg_slot[s] >= 0) {
            const int sslot = seg_slot[s];
#pragma unroll
            for (int qi = 0; qi < 2; qi++) {
                float l = l_vec[qi];
                l += __shfl_xor(l, 16);
                l += __shfl_xor(l, 32);
                int row_l = wave * 32 + qi * 16 + l15;    // 0..255
                if (lane < 16)
                    atomicAdd(&l_slot[sslot * 256 + row_l], l);
#pragma unroll
                for (int df = 0; df < 8; df++)
#pragma unroll
                    for (int r = 0; r < 4; r++)
                        atomicAdd(&o_slot[((size_t)sslot * 256 + row_l) * 128
                                          + df * 16 + quad * 4 + r], o[qi][df][r]);
            }
        } else {
#pragma unroll
            for (int qi = 0; qi < 2; qi++) {
                float l = l_vec[qi];
                l += __shfl_xor(l, 16);
                l += __shfl_xor(l, 32);
                float inv = 1.0f / l;
                int row = q0 + wave * 32 + qi * 16 + l15;
#pragma unroll
                for (int df = 0; df < 8; df++) {
                    ushort4 pk4;
                    pk4.x = f2bf(o[qi][df][0] * inv);
                    pk4.y = f2bf(o[qi][df][1] * inv);
                    pk4.z = f2bf(o[qi][df][2] * inv);
                    pk4.w = f2bf(o[qi][df][3] * inv);
                    *(ushort4*)(out + (size_t)row * (NHEAD * DHEAD) + head * DHEAD
                                + df * 16 + quad * 4) = pk4;
                }
            }
        }
    }
}

// ---------------------------------------------------------------------------
// Normalize split-strip slots -> attn (bf16). 256-row slots.
// slots 0..127: heavy strip of (head, p) -> q0 = (15-p)*256
// slots 128..191: light strips of p 4..7 -> q0 = p*256
// ---------------------------------------------------------------------------
__global__ __launch_bounds__(256)
void fixup_norm(const float* __restrict__ o_slot, const float* __restrict__ l_slot,
                ushort* __restrict__ attn)
{
    const int slot = blockIdx.x;          // 0..191
    int head, q0;
    if (slot < 128) {
        head = slot >> 3;
        q0   = (15 - (slot & 7)) * 256;
    } else {
        int s = slot - 128;
        head = s >> 2;
        q0   = (4 + (s & 3)) * 256;
    }
    const int t = threadIdx.x;
#pragma unroll 4
    for (int i = 0; i < 128; i++) {
        int idx = i * 256 + t;            // 0..32767
        int row = idx >> 7, d = idx & 127;
        float l = l_slot[slot * 256 + row];
        float v = o_slot[(size_t)slot * 32768 + idx] / l;
        attn[(size_t)(q0 + row) * HID_DIM + head * DHEAD + d] = f2bf(v);
    }
}

// ---------------------------------------------------------------------------
extern "C" void kernel_launch(void* const* d_in, const int* in_sizes, int n_in,
                              void* d_out, int out_size, void* d_ws, size_t ws_size,
                              hipStream_t stream)
{
    const float* x     = (const float*)d_in[0];
    const float* wqkv  = (const float*)d_in[1];
    const float* wproj = (const float*)d_in[2];
    float* outp = (float*)d_out;

    const size_t n_x     = (size_t)S_LEN * HID_DIM;     // 8,388,608
    const size_t n_wqkv  = (size_t)TOTAL * HID_DIM;     // 6,291,456
    const size_t n_wproj = (size_t)HID_DIM * HID_DIM;   // 4,194,304
    const size_t n_qkv   = (size_t)S_LEN * TOTAL;
    const size_t n_attn  = (size_t)S_LEN * HID_DIM;

    ushort* xb     = (ushort*)d_ws;                     // dead after GEMM1
    ushort* wqkvb  = xb + n_x;                          // dead after GEMM1
    ushort* qkv    = wqkvb + n_wqkv;
    ushort* attn   = qkv + n_qkv;
    ushort* vt     = attn + n_attn;                     // [4][128][4096]
    // reuse dead regions during/after flash:
    // o_slot+l_slot = 192*32768*4 + 192*256*4 = 25.36 MB <= xb+wqkvb (29.36 MB)
    float* o_slot  = (float*)d_ws;
    float* l_slot  = o_slot + (size_t)NSLOT * 32768;
    ushort* wprojb = wqkvb;                             // converted after fixup

    cvt_f32_bf16<<<2048, 256, 0, stream>>>(x, xb, (int)(n_x / 4), 0);
    cvt_f32_bf16<<<2048, 256, 0, stream>>>(wqkv, wqkvb, (int)(n_wqkv / 4), 1);

    // 1) qkv = x @ wqkv^T (+ V^T side-write)
    gemm_bt<ushort, true><<<dim3(TOTAL / 128, S_LEN / 128), 256, 0, stream>>>(
        xb, wqkvb, qkv, vt, S_LEN, TOTAL, HID_DIM);

    // zero the partial-accumulation slots (xb/wqkvb now dead); o+l contiguous
    zero_f4<<<2048, 256, 0, stream>>>((float4*)o_slot,
                                      (int)(((size_t)NSLOT * 32768 + NSLOT * 256) / 4));

    // 2) attention (512 blocks x 8 waves, 2/CU, in-register P pipeline)
    flash_attn<<<512, 512, 0, stream>>>(qkv, vt, attn, o_slot, l_slot);
    fixup_norm<<<NSLOT, 256, 0, stream>>>(o_slot, l_slot, attn);

    // 3) convert wproj (into dead wqkvb region), then out = attn @ wproj^T
    cvt_f32_bf16<<<2048, 256, 0, stream>>>(wproj, wprojb, (int)(n_wproj / 4), 0);
    gemm_bt<float, false><<<dim3(HID_DIM / 128, S_LEN / 128), 256, 0, stream>>>(
        attn, wprojb, outp, nullptr, S_LEN, HID_DIM, HID_DIM);
}

// Round 10
// 530.104 us; speedup vs baseline: 1.0009x; 1.0009x over previous
//
#include <hip/hip_runtime.h>
#include <hip/hip_bf16.h>
#include <stdint.h>

typedef __attribute__((ext_vector_type(8))) short short8;
typedef __attribute__((ext_vector_type(4))) float f32x4;

#define S_LEN   4096
#define HID_DIM 2048
#define NHEAD   16
#define NKV     4
#define DHEAD   128
#define QPG     4
#define GROUP   768   // (QPG+2)*DHEAD
#define TOTAL   3072  // NKV*GROUP

#define NSLOT   192   // 128 heavy + 64 light (pairs 4..7), 256-row slots

__device__ __forceinline__ ushort f2bf(float f) {
    union { float f; uint32_t u; } c; c.f = f;
    uint32_t u = c.u;
    u += 0x7fff + ((u >> 16) & 1);   // RNE
    return (ushort)(u >> 16);
}

// packed f32x2 -> bf16x2 (T12 recipe: no builtin on gfx950, asm is the idiom)
__device__ __forceinline__ uint32_t cvt_pk_bf16(float lo, float hi) {
    uint32_t r;
    asm("v_cvt_pk_bf16_f32 %0, %1, %2" : "=v"(r) : "v"(lo), "v"(hi));
    return r;
}

__device__ __forceinline__ void gld_lds16(const void* g, void* l) {
    __builtin_amdgcn_global_load_lds(
        (const __attribute__((address_space(1))) void*)g,
        (__attribute__((address_space(3))) void*)l, 16, 0, 0);
}

// LDS-only barrier: staged K/V visibility via lgkmcnt(0); register-destined
// global prefetch loads may stay in flight (R6: neutral vs full drain).
__device__ __forceinline__ void lds_barrier() {
    asm volatile("s_waitcnt lgkmcnt(0)\n\ts_barrier" ::: "memory");
}

// ---------------------------------------------------------------------------
// fp32 -> bf16 convert. mode 1: scale q-head rows of wqkv by 1/sqrt(D)
// ---------------------------------------------------------------------------
__global__ __launch_bounds__(256)
void cvt_f32_bf16(const float* __restrict__ src, ushort* __restrict__ dst,
                  int n4, int mode)
{
    int i = blockIdx.x * blockDim.x + threadIdx.x;
    int stride = gridDim.x * blockDim.x;
    for (; i < n4; i += stride) {
        float sc = 1.0f;
        if (mode == 1) {
            int row = i >> 9;                      // (i*4)/2048
            sc = ((row % GROUP) < QPG * DHEAD) ? 0.088388347648318447f : 1.0f;
        }
        float4 v = ((const float4*)src)[i];
        ushort4 o;
        o.x = f2bf(v.x * sc); o.y = f2bf(v.y * sc);
        o.z = f2bf(v.z * sc); o.w = f2bf(v.w * sc);
        ((ushort4*)dst)[i] = o;
    }
}

__global__ __launch_bounds__(256)
void zero_f4(float4* __restrict__ p, int n4)
{
    int i = blockIdx.x * blockDim.x + threadIdx.x;
    int stride = gridDim.x * blockDim.x;
    float4 z = {0.f, 0.f, 0.f, 0.f};
    for (; i < n4; i += stride) p[i] = z;
}

// ---------------------------------------------------------------------------
// C[M,N] = A[M,K] * B[N,K]^T (bf16 in, fp32 accum). m97-style staging.
// ---------------------------------------------------------------------------
__device__ __forceinline__ void store_c(ushort* C, size_t idx, float v) { C[idx] = f2bf(v); }
__device__ __forceinline__ void store_c(float*  C, size_t idx, float v) { C[idx] = v; }

template <typename OutT, bool WRITE_VT>
__global__ __launch_bounds__(256, 2)
void gemm_bt(const ushort* __restrict__ A, const ushort* __restrict__ B,
             OutT* __restrict__ C, ushort* __restrict__ VT,
             int M, int N, int K)
{
    __shared__ alignas(16) ushort Asl[128 * 32];
    __shared__ alignas(16) ushort Bsl[128 * 32];

    const int tid  = threadIdx.x;
    const int wave = tid >> 6;
    const int lane = tid & 63;
    const int quad = lane >> 4;
    const int l15  = lane & 15;
    const int wr   = wave >> 1;
    const int wc   = wave & 1;
    const int m0   = blockIdx.y * 128;
    const int n0   = blockIdx.x * 128;

    f32x4 acc[4][4];
#pragma unroll
    for (int i = 0; i < 4; i++)
#pragma unroll
        for (int j = 0; j < 4; j++) acc[i][j] = (f32x4)0.0f;

    for (int kb = 0; kb < K; kb += 32) {
        __syncthreads();
#pragma unroll
        for (int r = 0; r < 2; r++) {
            int idx = tid + r * 256;
            int row = idx >> 2, c8 = idx & 3;
            char* la = (char*)Asl + (size_t)(wave * 64 + r * 256) * 16;
            char* lb = (char*)Bsl + (size_t)(wave * 64 + r * 256) * 16;
            gld_lds16(A + (size_t)(m0 + row) * K + kb + c8 * 8, la);
            gld_lds16(B + (size_t)(n0 + row) * K + kb + c8 * 8, lb);
        }
        __syncthreads();

        short8 af[4], bf[4];
#pragma unroll
        for (int i = 0; i < 4; i++)
            af[i] = *(const short8*)(&Asl[(wr * 64 + i * 16 + l15) * 32 + quad * 8]);
#pragma unroll
        for (int j = 0; j < 4; j++)
            bf[j] = *(const short8*)(&Bsl[(wc * 64 + j * 16 + l15) * 32 + quad * 8]);
#pragma unroll
        for (int i = 0; i < 4; i++)
#pragma unroll
            for (int j = 0; j < 4; j++)
                acc[i][j] = __builtin_amdgcn_mfma_f32_16x16x32_bf16(
                    af[i], bf[j], acc[i][j], 0, 0, 0);
    }

#pragma unroll
    for (int i = 0; i < 4; i++)
#pragma unroll
        for (int j = 0; j < 4; j++)
#pragma unroll
            for (int r = 0; r < 4; r++) {
                int row = m0 + wr * 64 + i * 16 + quad * 4 + r;
                int col = n0 + wc * 64 + j * 16 + l15;
                store_c(C, (size_t)row * N + col, acc[i][j][r]);
            }

    if (WRITE_VT) {
        int cb = n0 >> 7;
        if (cb % 6 == 5) {          // V-region column block
            int g = cb / 6;
#pragma unroll
            for (int i = 0; i < 4; i++)
#pragma unroll
                for (int j = 0; j < 4; j++) {
                    int d    = wc * 64 + j * 16 + l15;
                    int row0 = m0 + wr * 64 + i * 16 + quad * 4;
                    ushort4 pk;
                    pk.x = f2bf(acc[i][j][0]); pk.y = f2bf(acc[i][j][1]);
                    pk.z = f2bf(acc[i][j][2]); pk.w = f2bf(acc[i][j][3]);
                    *(ushort4*)(VT + (size_t)(g * 128 + d) * S_LEN + row0) = pk;
                }
        }
    }
}

// ---------------------------------------------------------------------------
// Causal GQA flash attention. R8's winning 8-wave dbuf pipeline (512 thr,
// 256-row Q strips, 32-row KV tiles, 1 lgkm-barrier/tile, 2 blocks/CU),
// with the Pl LDS round-trip removed via swapped QK^T + SHUFFLE-built
// B-fragments -- PV stays on the PROVEN mfma_f32_16x16x32_bf16 builtin
// (R7/R9 post-mortem: the 16x16x16 path fell to inline asm "+v" and spilled
// the accumulators, VGPR 84 + 300-400 MB scratch; never use it).
//   S^T = mfma(K, Q): lane holds S^T[kv = ki*16+quad*4+r][q = l15]
//   softmax + cvt_pk in-lane -> P^T bf16 pairs (w0..w3 per qi)
//   B-frag build: lane (quad,l15) needs P^T[k=quad*8..+7][q=l15]; source
//   lane = quad_src = (k%16)>>2 at same l15, register chosen by ki=k>>4.
//   8 __shfl + 4 cndmask per qi replace 32 ds_write + lgkm wait + 2 ds_read.
//   O^T += mfma(V^T_frag, P_frag): A = Vt[df*16+l15][quad*8] (R8's pattern),
//   D = O^T[d = df*16+quad*4+r][q = l15] (R9's correctness-proven epilogue).
// LDS pin keeps the block at 55,296 B so the occupancy environment is
// identical to R8 (2 blocks/CU, 16 waves/CU).
// Geometry/slots identical to R8: (head, pair p, quarter), heavy 15-p
// (H = 128-8p) ++ light p (L = 8p+8) = 136 = 4*34 units; NSLOT = 192.
// ---------------------------------------------------------------------------
__global__ __launch_bounds__(512, 2)
void flash_attn(const ushort* __restrict__ qkv, const ushort* __restrict__ VT,
                ushort* __restrict__ out, float* __restrict__ o_slot,
                float* __restrict__ l_slot)
{
    const int b    = blockIdx.x;
    const int head = b >> 5;                  // head-major
    const int pair = (b >> 2) & 7;            // 0..7
    const int quar = b & 3;                   // 0..3

    const int g    = head >> 2;
    const int qh   = head & 3;
    const int H    = 128 - 8 * pair;          // heavy strip tiles (72..128)
    const int L    = 8 * pair + 8;            // light strip tiles (8..64)
    const int c0   = quar * 34;
    const int c1   = c0 + 34;

    const int tid  = threadIdx.x;
    const int wave = tid >> 6;                // 0..7
    const int lane = tid & 63;
    const int quad = lane >> 4;
    const int l15  = lane & 15;

    __shared__ alignas(16) ushort Kl[2][32][136];   // [buf][j][d]   17,408 B
    __shared__ alignas(16) ushort Vt[2][128][40];   // [buf][d][j]   20,480 B
    __shared__ alignas(16) ushort ldspin[8704];     // occupancy pin  17,408 B
    asm volatile("" :: "v"((uintptr_t)&ldspin[0])); // keep pin allocated

    int seg_s[2], seg_t0[2], seg_t1[2], seg_slot[2];
    int nseg = 0;
    {
        int h1 = (c1 < H) ? c1 : H;           // heavy piece [c0, h1)
        if (c0 < h1) {
            seg_s[nseg] = 15 - pair; seg_t0[nseg] = c0; seg_t1[nseg] = h1;
            seg_slot[nseg] = head * 8 + pair;           // heavy slot 0..127
            nseg++;
        }
        int l0 = (c0 > H) ? c0 : H;           // light piece [l0, c1) global units
        if (l0 < c1) {
            int lt0 = l0 - H, lt1 = c1 - H;
            int whole = (lt0 == 0) & (lt1 == L);        // pairs 0..3
            seg_s[nseg] = pair; seg_t0[nseg] = lt0; seg_t1[nseg] = lt1;
            seg_slot[nseg] = whole ? -1 : (128 + head * 4 + (pair - 4));
            nseg++;
        }
    }

    const int koff = g * GROUP + QPG * DHEAD;
    // shuffle sources for B-frag build (lane-invariant per thread)
    const int src0 = ((quad & 1) * 2) * 16 + l15;   // quad_src for k-octet lo
    const int src1 = src0 + 16;                     // quad_src for k-octet hi
    const bool hi_ki = (quad >= 2);                 // this lane's k>=16 -> ki=1

    for (int s = 0; s < nseg; s++) {
        const int t0 = seg_t0[s];
        const int t1 = seg_t1[s];
        const int q0 = seg_s[s] * 256;

        // Q fragments (B-operand of swapped QK^T: lane q-row = l15)
        short8 qf[2][4];
#pragma unroll
        for (int qi = 0; qi < 2; qi++) {
            int row = q0 + wave * 32 + qi * 16 + l15;
            const ushort* qp = qkv + (size_t)row * TOTAL + g * GROUP + qh * DHEAD + quad * 8;
#pragma unroll
            for (int ks = 0; ks < 4; ks++)
                qf[qi][ks] = *(const short8*)(qp + ks * 32);
        }

        f32x4 o[2][8];                        // O^T acc: [qi][df]
#pragma unroll
        for (int qi = 0; qi < 2; qi++)
#pragma unroll
            for (int df = 0; df < 8; df++) o[qi][df] = (f32x4)0.0f;
        float l_vec[2] = {0.0f, 0.0f};

        // per-thread staging slots (32-row tile: 512 f4 K + 512 f4 V, 512 thr)
        const int kr = tid >> 4, kc = tid & 15;       // K rows 0..31
        const int vd = tid >> 2, vc = tid & 3;        // V rows 0..127

        float4 kpre, vpre;
        // prologue: load tile t0, write buf 0, prefetch t0+1
        kpre = *(const float4*)(qkv + (size_t)(t0 * 32 + kr) * TOTAL + koff + kc * 8);
        vpre = *(const float4*)(VT + (size_t)(g * 128 + vd) * S_LEN + t0 * 32 + vc * 8);
        *(float4*)(&Kl[0][kr][kc * 8]) = kpre;
        *(float4*)(&Vt[0][vd][vc * 8]) = vpre;
        if (t0 + 1 < t1) {
            const int j1 = (t0 + 1) * 32;
            kpre = *(const float4*)(qkv + (size_t)(j1 + kr) * TOTAL + koff + kc * 8);
            vpre = *(const float4*)(VT + (size_t)(g * 128 + vd) * S_LEN + j1 + vc * 8);
        }
        __syncthreads();

        for (int t = t0; t < t1; t++) {
            const int cur = (t - t0) & 1;

            // stage tile t+1 into the other buffer (overlaps this compute)
            if (t + 1 < t1) {
                *(float4*)(&Kl[cur ^ 1][kr][kc * 8]) = kpre;
                *(float4*)(&Vt[cur ^ 1][vd][vc * 8]) = vpre;
                if (t + 2 < t1) {
                    const int j2 = (t + 2) * 32;
                    kpre = *(const float4*)(qkv + (size_t)(j2 + kr) * TOTAL + koff + kc * 8);
                    vpre = *(const float4*)(VT + (size_t)(g * 128 + vd) * S_LEN + j2 + vc * 8);
                }
            }

            const int j0 = t * 32;
            // S^T = K Q^T : sacc[ki][qi], lane: kv = ki*16 + quad*4 + r, q = l15
            f32x4 sacc[2][2];
#pragma unroll
            for (int ki = 0; ki < 2; ki++)
#pragma unroll
                for (int qi = 0; qi < 2; qi++) sacc[ki][qi] = (f32x4)0.0f;
            __builtin_amdgcn_s_setprio(1);
#pragma unroll
            for (int ki = 0; ki < 2; ki++)
#pragma unroll
                for (int ks = 0; ks < 4; ks++) {
                    short8 kf = *(const short8*)(&Kl[cur][ki * 16 + l15][ks * 32 + quad * 8]);
#pragma unroll
                    for (int qi = 0; qi < 2; qi++)
                        sacc[ki][qi] = __builtin_amdgcn_mfma_f32_16x16x32_bf16(
                            kf, qf[qi][ks], sacc[ki][qi], 0, 0, 0);
                }
            __builtin_amdgcn_s_setprio(0);

            // softmax in-lane + causal mask + P^T pack + shuffle B-frag build
            short8 pfrag[2];
#pragma unroll
            for (int qi = 0; qi < 2; qi++) {
                const int qmin = q0 + wave * 32 + qi * 16;   // wave-uniform
                float rs = 0.0f;
                if (j0 + 31 > qmin) {
                    const int q_g = qmin + l15;
#pragma unroll
                    for (int ki = 0; ki < 2; ki++)
#pragma unroll
                        for (int r = 0; r < 4; r++) {
                            float e = __expf(sacc[ki][qi][r]);
                            int kv_g = j0 + ki * 16 + quad * 4 + r;
                            e = (kv_g > q_g) ? 0.0f : e;
                            sacc[ki][qi][r] = e;
                            rs += e;
                        }
                } else {
#pragma unroll
                    for (int ki = 0; ki < 2; ki++)
#pragma unroll
                        for (int r = 0; r < 4; r++) {
                            float e = __expf(sacc[ki][qi][r]);
                            sacc[ki][qi][r] = e;
                            rs += e;
                        }
                }
                l_vec[qi] += rs;

                // pack: w0/w1 = ki0 halves, w2/w3 = ki1 halves (k = ki*16+quad*4+{..})
                uint32_t w0 = cvt_pk_bf16(sacc[0][qi][0], sacc[0][qi][1]);
                uint32_t w1 = cvt_pk_bf16(sacc[0][qi][2], sacc[0][qi][3]);
                uint32_t w2 = cvt_pk_bf16(sacc[1][qi][0], sacc[1][qi][1]);
                uint32_t w3 = cvt_pk_bf16(sacc[1][qi][2], sacc[1][qi][3]);
                // gather the two source quads' halves for this lane's k-octet
                uint32_t a0 = __shfl(w0, src0), a1 = __shfl(w1, src0);
                uint32_t a2 = __shfl(w0, src1), a3 = __shfl(w1, src1);
                uint32_t c0_ = __shfl(w2, src0), c1_ = __shfl(w3, src0);
                uint32_t c2_ = __shfl(w2, src1), c3_ = __shfl(w3, src1);
                union { uint32_t u[4]; short8 v; } bfu;
                bfu.u[0] = hi_ki ? c0_ : a0;
                bfu.u[1] = hi_ki ? c1_ : a1;
                bfu.u[2] = hi_ki ? c2_ : a2;
                bfu.u[3] = hi_ki ? c3_ : a3;
                pfrag[qi] = bfu.v;            // B[k = quad*8+j][q = l15]
            }

            // O^T += V^T P : A = Vt[df*16+l15][quad*8] (R8's proven pattern)
            __builtin_amdgcn_s_setprio(1);
#pragma unroll
            for (int df = 0; df < 8; df++) {
                short8 vf = *(const short8*)(&Vt[cur][df * 16 + l15][quad * 8]);
#pragma unroll
                for (int qi = 0; qi < 2; qi++)
                    o[qi][df] = __builtin_amdgcn_mfma_f32_16x16x32_bf16(
                        vf, pfrag[qi], o[qi][df], 0, 0, 0);
            }
            __builtin_amdgcn_s_setprio(0);

            // buf^1 staged for next iter; prefetch stays in flight.
            lds_barrier();
        }

        // epilogue. O^T lane layout: d = df*16 + quad*4 + r, q = l15 (+16qi).
        if (seg_slot[s] >= 0) {
            const int sslot = seg_slot[s];
#pragma unroll
            for (int qi = 0; qi < 2; qi++) {
                float l = l_vec[qi];
                l += __shfl_xor(l, 16);
                l += __shfl_xor(l, 32);
                int row_l = wave * 32 + qi * 16 + l15;    // 0..255
                if (lane < 16)
                    atomicAdd(&l_slot[sslot * 256 + row_l], l);
#pragma unroll
                for (int df = 0; df < 8; df++)
#pragma unroll
                    for (int r = 0; r < 4; r++)
                        atomicAdd(&o_slot[((size_t)sslot * 256 + row_l) * 128
                                          + df * 16 + quad * 4 + r], o[qi][df][r]);
            }
        } else {
#pragma unroll
            for (int qi = 0; qi < 2; qi++) {
                float l = l_vec[qi];
                l += __shfl_xor(l, 16);
                l += __shfl_xor(l, 32);
                float inv = 1.0f / l;
                int row = q0 + wave * 32 + qi * 16 + l15;
#pragma unroll
                for (int df = 0; df < 8; df++) {
                    ushort4 pk4;
                    pk4.x = f2bf(o[qi][df][0] * inv);
                    pk4.y = f2bf(o[qi][df][1] * inv);
                    pk4.z = f2bf(o[qi][df][2] * inv);
                    pk4.w = f2bf(o[qi][df][3] * inv);
                    *(ushort4*)(out + (size_t)row * (NHEAD * DHEAD) + head * DHEAD
                                + df * 16 + quad * 4) = pk4;
                }
            }
        }
    }
}

// ---------------------------------------------------------------------------
// Normalize split-strip slots -> attn (bf16). 256-row slots.
// slots 0..127: heavy strip of (head, p) -> q0 = (15-p)*256
// slots 128..191: light strips of p 4..7 -> q0 = p*256
// ---------------------------------------------------------------------------
__global__ __launch_bounds__(256)
void fixup_norm(const float* __restrict__ o_slot, const float* __restrict__ l_slot,
                ushort* __restrict__ attn)
{
    const int slot = blockIdx.x;          // 0..191
    int head, q0;
    if (slot < 128) {
        head = slot >> 3;
        q0   = (15 - (slot & 7)) * 256;
    } else {
        int s = slot - 128;
        head = s >> 2;
        q0   = (4 + (s & 3)) * 256;
    }
    const int t = threadIdx.x;
#pragma unroll 4
    for (int i = 0; i < 128; i++) {
        int idx = i * 256 + t;            // 0..32767
        int row = idx >> 7, d = idx & 127;
        float l = l_slot[slot * 256 + row];
        float v = o_slot[(size_t)slot * 32768 + idx] / l;
        attn[(size_t)(q0 + row) * HID_DIM + head * DHEAD + d] = f2bf(v);
    }
}

// ---------------------------------------------------------------------------
extern "C" void kernel_launch(void* const* d_in, const int* in_sizes, int n_in,
                              void* d_out, int out_size, void* d_ws, size_t ws_size,
                              hipStream_t stream)
{
    const float* x     = (const float*)d_in[0];
    const float* wqkv  = (const float*)d_in[1];
    const float* wproj = (const float*)d_in[2];
    float* outp = (float*)d_out;

    const size_t n_x     = (size_t)S_LEN * HID_DIM;     // 8,388,608
    const size_t n_wqkv  = (size_t)TOTAL * HID_DIM;     // 6,291,456
    const size_t n_wproj = (size_t)HID_DIM * HID_DIM;   // 4,194,304
    const size_t n_qkv   = (size_t)S_LEN * TOTAL;
    const size_t n_attn  = (size_t)S_LEN * HID_DIM;

    ushort* xb     = (ushort*)d_ws;                     // dead after GEMM1
    ushort* wqkvb  = xb + n_x;                          // dead after GEMM1
    ushort* qkv    = wqkvb + n_wqkv;
    ushort* attn   = qkv + n_qkv;
    ushort* vt     = attn + n_attn;                     // [4][128][4096]
    // reuse dead regions during/after flash:
    // o_slot+l_slot = 192*32768*4 + 192*256*4 = 25.36 MB <= xb+wqkvb (29.36 MB)
    float* o_slot  = (float*)d_ws;
    float* l_slot  = o_slot + (size_t)NSLOT * 32768;
    ushort* wprojb = wqkvb;                             // converted after fixup

    cvt_f32_bf16<<<2048, 256, 0, stream>>>(x, xb, (int)(n_x / 4), 0);
    cvt_f32_bf16<<<2048, 256, 0, stream>>>(wqkv, wqkvb, (int)(n_wqkv / 4), 1);

    // 1) qkv = x @ wqkv^T (+ V^T side-write)
    gemm_bt<ushort, true><<<dim3(TOTAL / 128, S_LEN / 128), 256, 0, stream>>>(
        xb, wqkvb, qkv, vt, S_LEN, TOTAL, HID_DIM);

    // zero the partial-accumulation slots (xb/wqkvb now dead); o+l contiguous
    zero_f4<<<2048, 256, 0, stream>>>((float4*)o_slot,
                                      (int)(((size_t)NSLOT * 32768 + NSLOT * 256) / 4));

    // 2) attention (512 blocks x 8 waves, 2/CU, shuffle-built in-register P)
    flash_attn<<<512, 512, 0, stream>>>(qkv, vt, attn, o_slot, l_slot);
    fixup_norm<<<NSLOT, 256, 0, stream>>>(o_slot, l_slot, attn);

    // 3) convert wproj (into dead wqkvb region), then out = attn @ wproj^T
    cvt_f32_bf16<<<2048, 256, 0, stream>>>(wproj, wprojb, (int)(n_wproj / 4), 0);
    gemm_bt<float, false><<<dim3(HID_DIM / 128, S_LEN / 128), 256, 0, stream>>>(
        attn, wprojb, outp, nullptr, S_LEN, HID_DIM, HID_DIM);
}